// Round 1
// baseline (709.437 us; speedup 1.0000x reference)
//
#include <hip/hip_runtime.h>
#include <math.h>

#define NPIX 16384
#define MODES 16384
#define BN_EPS 1e-5f

// ---------------- utility ----------------
__device__ __forceinline__ float wave_reduce(float v) {
#pragma unroll
    for (int off = 32; off; off >>= 1) v += __shfl_down(v, off);
    return v;
}

// ---------------- conv1 (1->16) + bn1 stats ----------------
__global__ void k_conv1(const float* __restrict__ x, const float* __restrict__ w,
                        const float* __restrict__ b, float* __restrict__ c1,
                        float* __restrict__ stats) {
    int p = blockIdx.x * 256 + threadIdx.x;
    int py = p >> 7, px = p & 127;
    float xn[9];
#pragma unroll
    for (int ky = 0; ky < 3; ++ky)
#pragma unroll
        for (int kx = 0; kx < 3; ++kx) {
            int yy = py + ky - 1, xx = px + kx - 1;
            xn[ky * 3 + kx] = (yy >= 0 && yy < 128 && xx >= 0 && xx < 128)
                                  ? x[yy * 128 + xx] : 0.f;
        }
    int lane = threadIdx.x & 63;
#pragma unroll
    for (int c = 0; c < 16; ++c) {
        float acc = b[c];
#pragma unroll
        for (int k = 0; k < 9; ++k) acc = fmaf(w[c * 9 + k], xn[k], acc);
        c1[c * NPIX + p] = acc;
        float s = wave_reduce(acc);
        float q = wave_reduce(acc * acc);
        if (lane == 0) {
            atomicAdd(&stats[c], s);
            atomicAdd(&stats[16 + c], q);
        }
    }
}

// ---------------- bn1+relu -> conv2 (16->32) + bn2 stats ----------------
__global__ void k_conv2(const float* __restrict__ c1, const float* __restrict__ stats1,
                        const float* __restrict__ g1, const float* __restrict__ bb1,
                        const float* __restrict__ w2, const float* __restrict__ b2,
                        float* __restrict__ c2, float* __restrict__ stats2) {
    int cg = blockIdx.x & 3;      // 8 output channels per group
    int chunk = blockIdx.x >> 2;  // 64 chunks of 256 pixels
    int p = chunk * 256 + threadIdx.x;
    int py = p >> 7, px = p & 127;

    float sc[16], sh[16];
#pragma unroll
    for (int ic = 0; ic < 16; ++ic) {
        float m = stats1[ic] * (1.f / 16384.f);
        float v = stats1[16 + ic] * (1.f / 16384.f) - m * m;
        float s = g1[ic] * rsqrtf(v + BN_EPS);
        sc[ic] = s;
        sh[ic] = bb1[ic] - m * s;
    }
    float acc[8];
#pragma unroll
    for (int o = 0; o < 8; ++o) acc[o] = b2[cg * 8 + o];

    for (int ic = 0; ic < 16; ++ic) {
        float nv[9];
#pragma unroll
        for (int ky = 0; ky < 3; ++ky)
#pragma unroll
            for (int kx = 0; kx < 3; ++kx) {
                int yy = py + ky - 1, xx = px + kx - 1;
                float v = 0.f;
                if (yy >= 0 && yy < 128 && xx >= 0 && xx < 128) {
                    v = fmaf(c1[ic * NPIX + yy * 128 + xx], sc[ic], sh[ic]);
                    v = fmaxf(v, 0.f);
                }
                nv[ky * 3 + kx] = v;
            }
#pragma unroll
        for (int o = 0; o < 8; ++o) {
            int oc = cg * 8 + o;
#pragma unroll
            for (int k = 0; k < 9; ++k)
                acc[o] = fmaf(w2[oc * 144 + ic * 9 + k], nv[k], acc[o]);
        }
    }
    int lane = threadIdx.x & 63;
#pragma unroll
    for (int o = 0; o < 8; ++o) {
        int oc = cg * 8 + o;
        c2[oc * NPIX + p] = acc[o];
        float s = wave_reduce(acc[o]);
        float q = wave_reduce(acc[o] * acc[o]);
        if (lane == 0) {
            atomicAdd(&stats2[oc], s);
            atomicAdd(&stats2[32 + oc], q);
        }
    }
}

// ---------------- bn2+relu -> conv3 (32->1) -> x_flat ----------------
__global__ void k_conv3(const float* __restrict__ c2, const float* __restrict__ stats2,
                        const float* __restrict__ g2, const float* __restrict__ bb2,
                        const float* __restrict__ w3, const float* __restrict__ b3,
                        float* __restrict__ xflat) {
    int p = blockIdx.x * 256 + threadIdx.x;
    int py = p >> 7, px = p & 127;
    float acc = b3[0];
    for (int ic = 0; ic < 32; ++ic) {
        float m = stats2[ic] * (1.f / 16384.f);
        float v = stats2[32 + ic] * (1.f / 16384.f) - m * m;
        float s = g2[ic] * rsqrtf(v + BN_EPS);
        float shf = bb2[ic] - m * s;
#pragma unroll
        for (int ky = 0; ky < 3; ++ky)
#pragma unroll
            for (int kx = 0; kx < 3; ++kx) {
                int yy = py + ky - 1, xx = px + kx - 1;
                float nv = 0.f;
                if (yy >= 0 && yy < 128 && xx >= 0 && xx < 128) {
                    nv = fmaf(c2[ic * NPIX + yy * 128 + xx], s, shf);
                    nv = fmaxf(nv, 0.f);
                }
                acc = fmaf(w3[ic * 9 + ky * 3 + kx], nv, acc);
            }
    }
    xflat[p] = acc;
}

// ---------------- GL weights: w_j = Gamma(j-a)/(Gamma(j+1)Gamma(-a)) * h^-a ----------------
__global__ void k_glw(float* __restrict__ glw) {
    int j = blockIdx.x * 256 + threadIdx.x;
    double scale = sqrt(16383.0);  // h^(-alpha), h=1/(n-1), alpha=0.5
    double wj;
    if (j == 0)
        wj = 1.0;
    else
        // Gamma(-0.5) = -2*sqrt(pi) = -3.5449077018110318
        wj = -exp(lgamma((double)j - 0.5) - lgamma((double)j + 1.0)) / 3.5449077018110318;
    glw[j] = (float)(wj * scale);
}

// ---------------- GL fractional: y[i] = sum_{j<=i} w[j] x[i-j], tiled ----------------
__global__ void k_glconv(const float* __restrict__ glw, const float* __restrict__ x,
                         float* __restrict__ y) {
    __shared__ float w_s[256];
    __shared__ float x_s[511];
    int bid = blockIdx.x;
    // map bid -> (bi, bj), 0 <= bj <= bi <= 63, bid = bi(bi+1)/2 + bj
    int bi = (int)((sqrtf(8.f * (float)bid + 1.f) - 1.f) * 0.5f);
    while ((bi + 1) * (bi + 2) / 2 <= bid) ++bi;
    while (bi * (bi + 1) / 2 > bid) --bi;
    int bj = bid - bi * (bi + 1) / 2;

    int ti = threadIdx.x;
    w_s[ti] = glw[256 * bj + ti];
    int xbase = 256 * (bi - bj) - 255;
#pragma unroll
    for (int k = ti; k < 511; k += 256) {
        int g = xbase + k;
        x_s[k] = (g >= 0) ? x[g] : 0.f;  // g <= 16383 always
    }
    __syncthreads();

    float p = 0.f;
#pragma unroll 8
    for (int jj = 0; jj < 256; ++jj)
        p = fmaf(w_s[jj], x_s[ti - jj + 255], p);

    atomicAdd(&y[256 * bi + ti], p);
}

// ---------------- GEMV: one block (256 thr) per row, long rows ----------------
template <bool RELU>
__global__ void gemv_block(const float* __restrict__ Wm, const float* __restrict__ bias,
                           const float* __restrict__ x, float* __restrict__ y, int N) {
    int row = blockIdx.x;
    const float4* Wr = reinterpret_cast<const float4*>(Wm + (size_t)row * N);
    const float4* xv = reinterpret_cast<const float4*>(x);
    int N4 = N >> 2;
    float acc = 0.f;
    for (int i = threadIdx.x; i < N4; i += 256) {
        float4 a = Wr[i];
        float4 b = xv[i];
        acc = fmaf(a.x, b.x, acc);
        acc = fmaf(a.y, b.y, acc);
        acc = fmaf(a.z, b.z, acc);
        acc = fmaf(a.w, b.w, acc);
    }
    __shared__ float red[4];
    float s = wave_reduce(acc);
    int wid = threadIdx.x >> 6, lane = threadIdx.x & 63;
    if (lane == 0) red[wid] = s;
    __syncthreads();
    if (threadIdx.x == 0) {
        float t = red[0] + red[1] + red[2] + red[3] + bias[row];
        if (RELU) t = fmaxf(t, 0.f);
        y[row] = t;
    }
}

// ---------------- GEMV: one wave per row, short rows (N=2048) ----------------
template <bool RELU>
__global__ void gemv_wave(const float* __restrict__ Wm, const float* __restrict__ bias,
                          const float* __restrict__ x, float* __restrict__ y, int N) {
    int wid = threadIdx.x >> 6, lane = threadIdx.x & 63;
    int row = blockIdx.x * 4 + wid;
    const float4* Wr = reinterpret_cast<const float4*>(Wm + (size_t)row * N);
    const float4* xv = reinterpret_cast<const float4*>(x);
    int N4 = N >> 2;
    float acc = 0.f;
    for (int i = lane; i < N4; i += 64) {
        float4 a = Wr[i];
        float4 b = xv[i];
        acc = fmaf(a.x, b.x, acc);
        acc = fmaf(a.y, b.y, acc);
        acc = fmaf(a.z, b.z, acc);
        acc = fmaf(a.w, b.w, acc);
    }
    float s = wave_reduce(acc);
    if (lane == 0) {
        float t = s + bias[row];
        if (RELU) t = fmaxf(t, 0.f);
        y[row] = t;
    }
}

// ---------------- launch ----------------
extern "C" void kernel_launch(void* const* d_in, const int* in_sizes, int n_in,
                              void* d_out, int out_size, void* d_ws, size_t ws_size,
                              hipStream_t stream) {
    const float* x       = (const float*)d_in[0];
    const float* conv1_w = (const float*)d_in[1];
    const float* conv1_b = (const float*)d_in[2];
    const float* bn1_g   = (const float*)d_in[3];
    const float* bn1_b   = (const float*)d_in[4];
    const float* conv2_w = (const float*)d_in[5];
    const float* conv2_b = (const float*)d_in[6];
    const float* bn2_g   = (const float*)d_in[7];
    const float* bn2_b   = (const float*)d_in[8];
    const float* conv3_w = (const float*)d_in[9];
    const float* conv3_b = (const float*)d_in[10];
    const float* enc_w1  = (const float*)d_in[11];
    const float* enc_b1  = (const float*)d_in[12];
    const float* enc_w2  = (const float*)d_in[13];
    const float* enc_b2  = (const float*)d_in[14];
    const float* enc_w3  = (const float*)d_in[15];
    const float* enc_b3  = (const float*)d_in[16];
    const float* op_w1   = (const float*)d_in[17];
    const float* op_b1   = (const float*)d_in[18];
    const float* op_w2   = (const float*)d_in[19];
    const float* op_b2   = (const float*)d_in[20];
    const float* op_w3   = (const float*)d_in[21];
    const float* op_b3   = (const float*)d_in[22];
    float* out = (float*)d_out;

    float* ws = (float*)d_ws;
    float* c1    = ws;            // 262144
    float* c2    = ws + 262144;   // 524288
    float* xflat = ws + 786432;   // 16384
    float* y1    = ws + 802816;   // 2048
    float* y2    = ws + 804864;   // 2048
    float* xfrac = ws + 806912;   // 16384
    float* glw   = ws + 823296;   // 16384
    float* z1    = ws + 839680;   // 2048
    float* z2    = ws + 841728;   // 2048
    float* xproc = ws + 843776;   // 16384  (atomic target, zeroed)
    float* stats = ws + 860160;   // 96: s1[16] q1[16] s2[32] q2[32]  (zeroed)

    // zero atomic-accumulation regions (xproc + stats contiguous: 16384+96 floats)
    hipMemsetAsync(xproc, 0, (16384 + 96) * sizeof(float), stream);

    // GL weights (independent of data path)
    k_glw<<<64, 256, 0, stream>>>(glw);

    // conv stack
    k_conv1<<<64, 256, 0, stream>>>(x, conv1_w, conv1_b, c1, stats);
    k_conv2<<<256, 256, 0, stream>>>(c1, stats, bn1_g, bn1_b, conv2_w, conv2_b,
                                     c2, stats + 32);
    k_conv3<<<64, 256, 0, stream>>>(c2, stats + 32, bn2_g, bn2_b, conv3_w, conv3_b,
                                    xflat);

    // encoder MLP
    gemv_block<true><<<2048, 256, 0, stream>>>(enc_w1, enc_b1, xflat, y1, 16384);
    gemv_wave<true><<<512, 256, 0, stream>>>(enc_w2, enc_b2, y1, y2, 2048);
    gemv_wave<false><<<4096, 256, 0, stream>>>(enc_w3, enc_b3, y2, xfrac, 2048);

    // GL fractional convolution
    k_glconv<<<2080, 256, 0, stream>>>(glw, xfrac, xproc);

    // operator MLP
    gemv_block<true><<<2048, 256, 0, stream>>>(op_w1, op_b1, xproc, z1, 16384);
    gemv_wave<true><<<512, 256, 0, stream>>>(op_w2, op_b2, z1, z2, 2048);
    gemv_wave<false><<<4096, 256, 0, stream>>>(op_w3, op_b3, z2, out, 2048);
}

// Round 3
// 603.270 us; speedup vs baseline: 1.1760x; 1.1760x over previous
//
#include <hip/hip_runtime.h>
#include <math.h>

#define NPIX 16384
#define BN_EPS 1e-5f

// ---------------- utility ----------------
__device__ __forceinline__ float wave_reduce(float v) {
#pragma unroll
    for (int off = 32; off; off >>= 1) v += __shfl_down(v, off);
    return v;
}

// ---------------- conv1 (1->16) + bn1 stats ----------------
// grid 64, block 256. Each block: 2 rows of 128 pixels. LDS-staged input tile.
__global__ void k_conv1(const float* __restrict__ x, const float* __restrict__ w,
                        const float* __restrict__ b, float* __restrict__ c1,
                        float* __restrict__ stats) {
    __shared__ float xs[4][132];
    __shared__ float rs[4][16], rq[4][16];
    int t = threadIdx.x;
    int r0 = blockIdx.x * 2;  // first output row
    // stage rows r0-1 .. r0+2, cols -1..128 (130 wide), zero-padded
#pragma unroll
    for (int r = 0; r < 4; ++r) {
        if (t < 130) {
            int gr = r0 - 1 + r, gc = t - 1;
            float v = 0.f;
            if (gr >= 0 && gr < 128 && gc >= 0 && gc < 128) v = x[gr * 128 + gc];
            xs[r][t] = v;
        }
    }
    __syncthreads();

    int pyl = t >> 7, px = t & 127;
    int p = r0 * 128 + t;
    float nv[9];
#pragma unroll
    for (int ky = 0; ky < 3; ++ky)
#pragma unroll
        for (int kx = 0; kx < 3; ++kx) nv[ky * 3 + kx] = xs[pyl + ky][px + kx];

    int wid = t >> 6, lane = t & 63;
#pragma unroll
    for (int c = 0; c < 16; ++c) {
        float acc = b[c];
#pragma unroll
        for (int k = 0; k < 9; ++k) acc = fmaf(w[c * 9 + k], nv[k], acc);
        c1[c * NPIX + p] = acc;
        float s = wave_reduce(acc);
        float q = wave_reduce(acc * acc);
        if (lane == 0) { rs[wid][c] = s; rq[wid][c] = q; }
    }
    __syncthreads();
    if (t < 16)
        atomicAdd(&stats[t], rs[0][t] + rs[1][t] + rs[2][t] + rs[3][t]);
    else if (t < 32)
        atomicAdd(&stats[t], rq[0][t - 16] + rq[1][t - 16] + rq[2][t - 16] + rq[3][t - 16]);
}

// ---------------- bn1+relu -> conv2 (16->32) + bn2 stats ----------------
// grid 128 = 64 pixel-chunks x 2 output-channel groups (16 each). block 256.
__global__ void k_conv2(const float* __restrict__ c1, const float* __restrict__ stats1,
                        const float* __restrict__ g1, const float* __restrict__ bb1,
                        const float* __restrict__ w2, const float* __restrict__ b2,
                        float* __restrict__ c2, float* __restrict__ stats2) {
    __shared__ float xs[16][4][132];
    __shared__ float rs[4][16], rq[4][16];
    int t = threadIdx.x;
    int cg = blockIdx.x & 1;
    int chunk = blockIdx.x >> 1;
    int r0 = chunk * 2;

    // stage bn1+relu(c1) tile: 16 channels, rows r0-1..r0+2, cols -1..128
    for (int ch = 0; ch < 16; ++ch) {
        float m = stats1[ch] * (1.f / 16384.f);
        float v = stats1[16 + ch] * (1.f / 16384.f) - m * m;
        float s = g1[ch] * rsqrtf(v + BN_EPS);
        float sh = bb1[ch] - m * s;
#pragma unroll
        for (int r = 0; r < 4; ++r) {
            if (t < 130) {
                int gr = r0 - 1 + r, gc = t - 1;
                float val = 0.f;
                if (gr >= 0 && gr < 128 && gc >= 0 && gc < 128)
                    val = fmaxf(fmaf(c1[ch * NPIX + gr * 128 + gc], s, sh), 0.f);
                xs[ch][r][t] = val;
            }
        }
    }
    __syncthreads();

    int pyl = t >> 7, px = t & 127;
    int p = r0 * 128 + t;
    float acc[16];
#pragma unroll
    for (int o = 0; o < 16; ++o) acc[o] = b2[cg * 16 + o];

    for (int ch = 0; ch < 16; ++ch) {
        float nv[9];
#pragma unroll
        for (int ky = 0; ky < 3; ++ky)
#pragma unroll
            for (int kx = 0; kx < 3; ++kx) nv[ky * 3 + kx] = xs[ch][pyl + ky][px + kx];
#pragma unroll
        for (int o = 0; o < 16; ++o) {
            int oc = cg * 16 + o;
#pragma unroll
            for (int k = 0; k < 9; ++k)
                acc[o] = fmaf(w2[oc * 144 + ch * 9 + k], nv[k], acc[o]);
        }
    }

    int wid = t >> 6, lane = t & 63;
#pragma unroll
    for (int o = 0; o < 16; ++o) {
        int oc = cg * 16 + o;
        c2[oc * NPIX + p] = acc[o];
        float s = wave_reduce(acc[o]);
        float q = wave_reduce(acc[o] * acc[o]);
        if (lane == 0) { rs[wid][o] = s; rq[wid][o] = q; }
    }
    __syncthreads();
    if (t < 16)
        atomicAdd(&stats2[cg * 16 + t], rs[0][t] + rs[1][t] + rs[2][t] + rs[3][t]);
    else if (t < 32)
        atomicAdd(&stats2[32 + cg * 16 + (t - 16)],
                  rq[0][t - 16] + rq[1][t - 16] + rq[2][t - 16] + rq[3][t - 16]);
}

// ---------------- bn2+relu -> conv3 (32->1) -> x_flat ----------------
// grid 128 (one output row each), block 256 (128 compute + all stage).
__global__ void k_conv3(const float* __restrict__ c2, const float* __restrict__ stats2,
                        const float* __restrict__ g2, const float* __restrict__ bb2,
                        const float* __restrict__ w3, const float* __restrict__ b3,
                        float* __restrict__ xflat) {
    __shared__ float xs[32][3][132];  // 50.7 KB
    int t = threadIdx.x;
    int row = blockIdx.x;

    for (int ch = 0; ch < 32; ++ch) {
        float m = stats2[ch] * (1.f / 16384.f);
        float v = stats2[32 + ch] * (1.f / 16384.f) - m * m;
        float s = g2[ch] * rsqrtf(v + BN_EPS);
        float sh = bb2[ch] - m * s;
#pragma unroll
        for (int r = 0; r < 3; ++r) {
            if (t < 130) {
                int gr = row - 1 + r, gc = t - 1;
                float val = 0.f;
                if (gr >= 0 && gr < 128 && gc >= 0 && gc < 128)
                    val = fmaxf(fmaf(c2[ch * NPIX + gr * 128 + gc], s, sh), 0.f);
                xs[ch][r][t] = val;
            }
        }
    }
    __syncthreads();

    if (t < 128) {
        float acc = b3[0];
        for (int ch = 0; ch < 32; ++ch) {
#pragma unroll
            for (int ky = 0; ky < 3; ++ky)
#pragma unroll
                for (int kx = 0; kx < 3; ++kx)
                    acc = fmaf(w3[ch * 9 + ky * 3 + kx], xs[ch][ky][t + kx], acc);
        }
        xflat[row * 128 + t] = acc;
    }
}

// ---------------- GL weights ----------------
__global__ void k_glw(float* __restrict__ glw) {
    int j = blockIdx.x * 256 + threadIdx.x;
    double scale = sqrt(16383.0);  // h^(-alpha), h=1/(n-1), alpha=0.5
    double wj;
    if (j == 0)
        wj = 1.0;
    else
        wj = -exp(lgamma((double)j - 0.5) - lgamma((double)j + 1.0)) / 3.5449077018110318;
    glw[j] = (float)(wj * scale);
}

// ---------------- GL fractional conv (triangular Toeplitz, tiled) ----------------
__global__ void k_glconv(const float* __restrict__ glw, const float* __restrict__ x,
                         float* __restrict__ y) {
    __shared__ float w_s[256];
    __shared__ float x_s[511];
    int bid = blockIdx.x;
    int bi = (int)((sqrtf(8.f * (float)bid + 1.f) - 1.f) * 0.5f);
    while ((bi + 1) * (bi + 2) / 2 <= bid) ++bi;
    while (bi * (bi + 1) / 2 > bid) --bi;
    int bj = bid - bi * (bi + 1) / 2;

    int ti = threadIdx.x;
    w_s[ti] = glw[256 * bj + ti];
    int xbase = 256 * (bi - bj) - 255;
#pragma unroll
    for (int k = ti; k < 511; k += 256) {
        int g = xbase + k;
        x_s[k] = (g >= 0) ? x[g] : 0.f;
    }
    __syncthreads();

    float p = 0.f;
#pragma unroll 8
    for (int jj = 0; jj < 256; ++jj)
        p = fmaf(w_s[jj], x_s[ti - jj + 255], p);

    atomicAdd(&y[256 * bi + ti], p);
}

// ---------------- GEMV: one block (256 thr) per row, long rows ----------------
template <int N, bool RELU>
__global__ void gemv_block(const float* __restrict__ Wm, const float* __restrict__ bias,
                           const float* __restrict__ x, float* __restrict__ y) {
    int row = blockIdx.x;
    const float4* Wr = reinterpret_cast<const float4*>(Wm + (size_t)row * N);
    const float4* xv = reinterpret_cast<const float4*>(x);
    constexpr int N4 = N >> 2;
    float acc = 0.f;
#pragma unroll 4
    for (int i = threadIdx.x; i < N4; i += 256) {
        float4 a = Wr[i];
        float4 b = xv[i];
        acc = fmaf(a.x, b.x, acc);
        acc = fmaf(a.y, b.y, acc);
        acc = fmaf(a.z, b.z, acc);
        acc = fmaf(a.w, b.w, acc);
    }
    __shared__ float red[4];
    float s = wave_reduce(acc);
    int wid = threadIdx.x >> 6, lane = threadIdx.x & 63;
    if (lane == 0) red[wid] = s;
    __syncthreads();
    if (threadIdx.x == 0) {
        float t = red[0] + red[1] + red[2] + red[3] + bias[row];
        if (RELU) t = fmaxf(t, 0.f);
        y[row] = t;
    }
}

// ---------------- GEMV: one wave per row, short rows ----------------
template <int N, bool RELU>
__global__ void gemv_wave(const float* __restrict__ Wm, const float* __restrict__ bias,
                          const float* __restrict__ x, float* __restrict__ y) {
    int wid = threadIdx.x >> 6, lane = threadIdx.x & 63;
    int row = blockIdx.x * 4 + wid;
    const float4* Wr = reinterpret_cast<const float4*>(Wm + (size_t)row * N);
    const float4* xv = reinterpret_cast<const float4*>(x);
    constexpr int N4 = N >> 2;
    float acc = 0.f;
#pragma unroll 4
    for (int i = lane; i < N4; i += 64) {
        float4 a = Wr[i];
        float4 b = xv[i];
        acc = fmaf(a.x, b.x, acc);
        acc = fmaf(a.y, b.y, acc);
        acc = fmaf(a.z, b.z, acc);
        acc = fmaf(a.w, b.w, acc);
    }
    float s = wave_reduce(acc);
    if (lane == 0) {
        float t = s + bias[row];
        if (RELU) t = fmaxf(t, 0.f);
        y[row] = t;
    }
}

// ---------------- launch ----------------
extern "C" void kernel_launch(void* const* d_in, const int* in_sizes, int n_in,
                              void* d_out, int out_size, void* d_ws, size_t ws_size,
                              hipStream_t stream) {
    const float* x       = (const float*)d_in[0];
    const float* conv1_w = (const float*)d_in[1];
    const float* conv1_b = (const float*)d_in[2];
    const float* bn1_g   = (const float*)d_in[3];
    const float* bn1_b   = (const float*)d_in[4];
    const float* conv2_w = (const float*)d_in[5];
    const float* conv2_b = (const float*)d_in[6];
    const float* bn2_g   = (const float*)d_in[7];
    const float* bn2_b   = (const float*)d_in[8];
    const float* conv3_w = (const float*)d_in[9];
    const float* conv3_b = (const float*)d_in[10];
    const float* enc_w1  = (const float*)d_in[11];
    const float* enc_b1  = (const float*)d_in[12];
    const float* enc_w2  = (const float*)d_in[13];
    const float* enc_b2  = (const float*)d_in[14];
    const float* enc_w3  = (const float*)d_in[15];
    const float* enc_b3  = (const float*)d_in[16];
    const float* op_w1   = (const float*)d_in[17];
    const float* op_b1   = (const float*)d_in[18];
    const float* op_w2   = (const float*)d_in[19];
    const float* op_b2   = (const float*)d_in[20];
    const float* op_w3   = (const float*)d_in[21];
    const float* op_b3   = (const float*)d_in[22];
    float* out = (float*)d_out;

    float* ws = (float*)d_ws;
    float* c1    = ws;            // 262144
    float* c2    = ws + 262144;   // 524288
    float* xflat = ws + 786432;   // 16384
    float* y1    = ws + 802816;   // 2048
    float* y2    = ws + 804864;   // 2048
    float* xfrac = ws + 806912;   // 16384
    float* glw   = ws + 823296;   // 16384
    float* z1    = ws + 839680;   // 2048
    float* z2    = ws + 841728;   // 2048
    float* xproc = ws + 843776;   // 16384  (atomic target, zeroed)
    float* stats = ws + 860160;   // 96: s1[16] q1[16] s2[32] q2[32]  (zeroed)

    hipMemsetAsync(xproc, 0, (16384 + 96) * sizeof(float), stream);

    k_glw<<<64, 256, 0, stream>>>(glw);

    k_conv1<<<64, 256, 0, stream>>>(x, conv1_w, conv1_b, c1, stats);
    k_conv2<<<128, 256, 0, stream>>>(c1, stats, bn1_g, bn1_b, conv2_w, conv2_b,
                                     c2, stats + 32);
    k_conv3<<<128, 256, 0, stream>>>(c2, stats + 32, bn2_g, bn2_b, conv3_w, conv3_b,
                                     xflat);

    gemv_block<16384, true><<<2048, 256, 0, stream>>>(enc_w1, enc_b1, xflat, y1);
    gemv_wave<2048, true><<<512, 256, 0, stream>>>(enc_w2, enc_b2, y1, y2);
    gemv_wave<2048, false><<<4096, 256, 0, stream>>>(enc_w3, enc_b3, y2, xfrac);

    k_glconv<<<2080, 256, 0, stream>>>(glw, xfrac, xproc);

    gemv_block<16384, true><<<2048, 256, 0, stream>>>(op_w1, op_b1, xproc, z1);
    gemv_wave<2048, true><<<512, 256, 0, stream>>>(op_w2, op_b2, z1, z2);
    gemv_wave<2048, false><<<4096, 256, 0, stream>>>(op_w3, op_b3, z2, out);
}

// Round 4
// 552.407 us; speedup vs baseline: 1.2843x; 1.0921x over previous
//
#include <hip/hip_runtime.h>
#include <math.h>

#define NPIX 16384
#define BN_EPS 1e-5f

// ---------------- utility ----------------
__device__ __forceinline__ float wave_reduce(float v) {
#pragma unroll
    for (int off = 32; off; off >>= 1) v += __shfl_down(v, off);
    return v;
}

// ---------------- GL weights + zero-init of atomic targets ----------------
// zr layout: [0,16384) xflat, [16384,32768) xproc, [32768,32864) stats
__global__ void k_glw(float* __restrict__ glw, float* __restrict__ zr) {
    int j = blockIdx.x * 256 + threadIdx.x;
    zr[j] = 0.f;
    zr[16384 + j] = 0.f;
    if (j < 96) zr[32768 + j] = 0.f;
    double wj;
    if (j == 0)
        wj = 1.0;
    else
        // w_j = Gamma(j-0.5)/(Gamma(j+1)*Gamma(-0.5)); Gamma(-0.5) = -2*sqrt(pi)
        wj = -exp(lgamma((double)j - 0.5) - lgamma((double)j + 1.0)) / 3.5449077018110318;
    glw[j] = (float)(wj * sqrt(16383.0));  // * h^(-alpha)
}

// ---------------- conv1 (1->16) + bn1 stats. grid 64, block 256 (2 rows) ----------------
__global__ void k_conv1(const float* __restrict__ x, const float* __restrict__ w,
                        const float* __restrict__ b, float* __restrict__ c1,
                        float* __restrict__ stats) {
    __shared__ float xs[4][132];
    __shared__ float rs[4][16], rq[4][16];
    int t = threadIdx.x;
    int r0 = blockIdx.x * 2;
    // flattened parallel staging: rows r0-1..r0+2, cols -1..128, zero-padded
    for (int idx = t; idx < 4 * 132; idx += 256) {
        int r = idx / 132, c = idx - r * 132;
        int gr = r0 - 1 + r, gc = c - 1;
        float v = 0.f;
        if (c < 130 && gr >= 0 && gr < 128 && gc >= 0 && gc < 128) v = x[gr * 128 + gc];
        xs[r][c] = v;
    }
    __syncthreads();

    int pyl = t >> 7, px = t & 127;
    int p = r0 * 128 + t;
    float nv[9];
#pragma unroll
    for (int ky = 0; ky < 3; ++ky)
#pragma unroll
        for (int kx = 0; kx < 3; ++kx) nv[ky * 3 + kx] = xs[pyl + ky][px + kx];

    int wid = t >> 6, lane = t & 63;
#pragma unroll
    for (int c = 0; c < 16; ++c) {
        float acc = b[c];
#pragma unroll
        for (int k = 0; k < 9; ++k) acc = fmaf(w[c * 9 + k], nv[k], acc);
        c1[c * NPIX + p] = acc;
        float s = wave_reduce(acc);
        float q = wave_reduce(acc * acc);
        if (lane == 0) { rs[wid][c] = s; rq[wid][c] = q; }
    }
    __syncthreads();
    if (t < 16)
        atomicAdd(&stats[t], rs[0][t] + rs[1][t] + rs[2][t] + rs[3][t]);
    else if (t < 32)
        atomicAdd(&stats[t], rq[0][t - 16] + rq[1][t - 16] + rq[2][t - 16] + rq[3][t - 16]);
}

// ---------------- bn1+relu -> conv2 (16->32) + bn2 stats ----------------
// grid 256 = 64 chunks(2 rows) x 4 out-channel groups (8 each). block 256.
__global__ void k_conv2(const float* __restrict__ c1, const float* __restrict__ stats1,
                        const float* __restrict__ g1, const float* __restrict__ bb1,
                        const float* __restrict__ w2, const float* __restrict__ b2,
                        float* __restrict__ c2, float* __restrict__ stats2) {
    __shared__ float xs[16][4][132];   // 33.8 KB
    __shared__ float scs[16], shs[16];
    __shared__ float rs[4][8], rq[4][8];
    int t = threadIdx.x;
    int cg = blockIdx.x & 3;
    int chunk = blockIdx.x >> 2;
    int r0 = chunk * 2;

    if (t < 16) {
        float m = stats1[t] * (1.f / 16384.f);
        float v = stats1[16 + t] * (1.f / 16384.f) - m * m;
        float s = g1[t] * rsqrtf(v + BN_EPS);
        scs[t] = s;
        shs[t] = bb1[t] - m * s;
    }
    __syncthreads();

    // flattened parallel staging of bn1+relu(c1): 16 ch x 4 rows x 130 cols
    for (int idx = t; idx < 16 * 4 * 132; idx += 256) {
        int ch = idx / 528;
        int rem = idx - ch * 528;
        int r = rem / 132, c = rem - r * 132;
        int gr = r0 - 1 + r, gc = c - 1;
        float val = 0.f;
        if (c < 130 && gr >= 0 && gr < 128 && gc >= 0 && gc < 128)
            val = fmaxf(fmaf(c1[ch * NPIX + gr * 128 + gc], scs[ch], shs[ch]), 0.f);
        xs[ch][r][c] = val;
    }
    __syncthreads();

    int pyl = t >> 7, px = t & 127;
    int p = r0 * 128 + t;
    float acc[8];
#pragma unroll
    for (int o = 0; o < 8; ++o) acc[o] = b2[cg * 8 + o];

    for (int ch = 0; ch < 16; ++ch) {
        float nv[9];
#pragma unroll
        for (int ky = 0; ky < 3; ++ky)
#pragma unroll
            for (int kx = 0; kx < 3; ++kx) nv[ky * 3 + kx] = xs[ch][pyl + ky][px + kx];
#pragma unroll
        for (int o = 0; o < 8; ++o) {
            int oc = cg * 8 + o;
#pragma unroll
            for (int k = 0; k < 9; ++k)
                acc[o] = fmaf(w2[oc * 144 + ch * 9 + k], nv[k], acc[o]);
        }
    }

    int wid = t >> 6, lane = t & 63;
#pragma unroll
    for (int o = 0; o < 8; ++o) {
        int oc = cg * 8 + o;
        c2[oc * NPIX + p] = acc[o];
        float s = wave_reduce(acc[o]);
        float q = wave_reduce(acc[o] * acc[o]);
        if (lane == 0) { rs[wid][o] = s; rq[wid][o] = q; }
    }
    __syncthreads();
    if (t < 8)
        atomicAdd(&stats2[cg * 8 + t], rs[0][t] + rs[1][t] + rs[2][t] + rs[3][t]);
    else if (t < 16)
        atomicAdd(&stats2[32 + cg * 8 + (t - 8)],
                  rq[0][t - 8] + rq[1][t - 8] + rq[2][t - 8] + rq[3][t - 8]);
}

// ---------------- bn2+relu -> conv3 (32->1) -> x_flat (atomic partial) ----------------
// grid 256 = 128 rows x 2 channel groups (16 each). block 256. xflat pre-zeroed.
__global__ void k_conv3(const float* __restrict__ c2, const float* __restrict__ stats2,
                        const float* __restrict__ g2, const float* __restrict__ bb2,
                        const float* __restrict__ w3, const float* __restrict__ b3,
                        float* __restrict__ xflat) {
    __shared__ float xs[16][3][132];   // 25.3 KB
    __shared__ float scs[16], shs[16];
    int t = threadIdx.x;
    int cg = blockIdx.x & 1;
    int row = blockIdx.x >> 1;
    int cb = cg * 16;

    if (t < 16) {
        int ch = cb + t;
        float m = stats2[ch] * (1.f / 16384.f);
        float v = stats2[32 + ch] * (1.f / 16384.f) - m * m;
        float s = g2[ch] * rsqrtf(v + BN_EPS);
        scs[t] = s;
        shs[t] = bb2[ch] - m * s;
    }
    __syncthreads();

    for (int idx = t; idx < 16 * 3 * 132; idx += 256) {
        int ch = idx / 396;
        int rem = idx - ch * 396;
        int r = rem / 132, c = rem - r * 132;
        int gr = row - 1 + r, gc = c - 1;
        float val = 0.f;
        if (c < 130 && gr >= 0 && gr < 128 && gc >= 0 && gc < 128)
            val = fmaxf(fmaf(c2[(cb + ch) * NPIX + gr * 128 + gc], scs[ch], shs[ch]), 0.f);
        xs[ch][r][c] = val;
    }
    __syncthreads();

    if (t < 128) {
        float acc = (cg == 0) ? b3[0] : 0.f;
        for (int ch = 0; ch < 16; ++ch) {
#pragma unroll
            for (int ky = 0; ky < 3; ++ky)
#pragma unroll
                for (int kx = 0; kx < 3; ++kx)
                    acc = fmaf(w3[(cb + ch) * 9 + ky * 3 + kx], xs[ch][ky][t + kx], acc);
        }
        atomicAdd(&xflat[row * 128 + t], acc);
    }
}

// ---------------- GL fractional conv (triangular Toeplitz, tiled) ----------------
__global__ void k_glconv(const float* __restrict__ glw, const float* __restrict__ x,
                         float* __restrict__ y) {
    __shared__ float w_s[256];
    __shared__ float x_s[511];
    int bid = blockIdx.x;
    int bi = (int)((sqrtf(8.f * (float)bid + 1.f) - 1.f) * 0.5f);
    while ((bi + 1) * (bi + 2) / 2 <= bid) ++bi;
    while (bi * (bi + 1) / 2 > bid) --bi;
    int bj = bid - bi * (bi + 1) / 2;

    int ti = threadIdx.x;
    w_s[ti] = glw[256 * bj + ti];
    int xbase = 256 * (bi - bj) - 255;
#pragma unroll
    for (int k = ti; k < 511; k += 256) {
        int g = xbase + k;
        x_s[k] = (g >= 0) ? x[g] : 0.f;
    }
    __syncthreads();

    float p = 0.f;
#pragma unroll 8
    for (int jj = 0; jj < 256; ++jj)
        p = fmaf(w_s[jj], x_s[ti - jj + 255], p);

    atomicAdd(&y[256 * bi + ti], p);
}

// ---------------- GEMV: one block (256 thr) per row of 16384 ----------------
template <bool RELU>
__global__ void gemv_block(const float* __restrict__ Wm, const float* __restrict__ bias,
                           const float* __restrict__ x, float* __restrict__ y) {
    int row = blockIdx.x;
    const float4* Wr = reinterpret_cast<const float4*>(Wm + (size_t)row * 16384);
    const float4* xv = reinterpret_cast<const float4*>(x);
    float acc = 0.f;
#pragma unroll 4
    for (int i = threadIdx.x; i < 4096; i += 256) {
        float4 a = Wr[i];
        float4 b = xv[i];
        acc = fmaf(a.x, b.x, acc);
        acc = fmaf(a.y, b.y, acc);
        acc = fmaf(a.z, b.z, acc);
        acc = fmaf(a.w, b.w, acc);
    }
    __shared__ float red[4];
    float s = wave_reduce(acc);
    int wid = threadIdx.x >> 6, lane = threadIdx.x & 63;
    if (lane == 0) red[wid] = s;
    __syncthreads();
    if (threadIdx.x == 0) {
        float t = red[0] + red[1] + red[2] + red[3] + bias[row];
        if (RELU) t = fmaxf(t, 0.f);
        y[row] = t;
    }
}

// ---------------- GEMV (N=2048): 2 rows per wave, shared x loads ----------------
// grid = nrows/8 blocks of 256 (4 waves x 2 rows).
template <bool RELU>
__global__ void gemv2(const float* __restrict__ Wm, const float* __restrict__ bias,
                      const float* __restrict__ x, float* __restrict__ y) {
    int wid = threadIdx.x >> 6, lane = threadIdx.x & 63;
    int r0 = (blockIdx.x * 4 + wid) * 2;
    const float4* W0 = reinterpret_cast<const float4*>(Wm + (size_t)r0 * 2048);
    const float4* W1 = reinterpret_cast<const float4*>(Wm + (size_t)(r0 + 1) * 2048);
    const float4* xv = reinterpret_cast<const float4*>(x);
    float a0 = 0.f, a1 = 0.f;
#pragma unroll
    for (int i = lane; i < 512; i += 64) {
        float4 b = xv[i];
        float4 u = W0[i];
        float4 v = W1[i];
        a0 = fmaf(u.x, b.x, a0); a0 = fmaf(u.y, b.y, a0);
        a0 = fmaf(u.z, b.z, a0); a0 = fmaf(u.w, b.w, a0);
        a1 = fmaf(v.x, b.x, a1); a1 = fmaf(v.y, b.y, a1);
        a1 = fmaf(v.z, b.z, a1); a1 = fmaf(v.w, b.w, a1);
    }
    a0 = wave_reduce(a0);
    a1 = wave_reduce(a1);
    if (lane == 0) {
        float t0 = a0 + bias[r0];
        float t1 = a1 + bias[r0 + 1];
        if (RELU) { t0 = fmaxf(t0, 0.f); t1 = fmaxf(t1, 0.f); }
        y[r0] = t0;
        y[r0 + 1] = t1;
    }
}

// ---------------- launch ----------------
extern "C" void kernel_launch(void* const* d_in, const int* in_sizes, int n_in,
                              void* d_out, int out_size, void* d_ws, size_t ws_size,
                              hipStream_t stream) {
    const float* x       = (const float*)d_in[0];
    const float* conv1_w = (const float*)d_in[1];
    const float* conv1_b = (const float*)d_in[2];
    const float* bn1_g   = (const float*)d_in[3];
    const float* bn1_b   = (const float*)d_in[4];
    const float* conv2_w = (const float*)d_in[5];
    const float* conv2_b = (const float*)d_in[6];
    const float* bn2_g   = (const float*)d_in[7];
    const float* bn2_b   = (const float*)d_in[8];
    const float* conv3_w = (const float*)d_in[9];
    const float* conv3_b = (const float*)d_in[10];
    const float* enc_w1  = (const float*)d_in[11];
    const float* enc_b1  = (const float*)d_in[12];
    const float* enc_w2  = (const float*)d_in[13];
    const float* enc_b2  = (const float*)d_in[14];
    const float* enc_w3  = (const float*)d_in[15];
    const float* enc_b3  = (const float*)d_in[16];
    const float* op_w1   = (const float*)d_in[17];
    const float* op_b1   = (const float*)d_in[18];
    const float* op_w2   = (const float*)d_in[19];
    const float* op_b2   = (const float*)d_in[20];
    const float* op_w3   = (const float*)d_in[21];
    const float* op_b3   = (const float*)d_in[22];
    float* out = (float*)d_out;

    float* ws = (float*)d_ws;
    // zero-init region first (written by k_glw): xflat, xproc, stats
    float* xflat = ws;            // 16384  (atomic target)
    float* xproc = ws + 16384;    // 16384  (atomic target)
    float* stats = ws + 32768;    // 96: s1[16] q1[16] | s2[32] q2[32]
    float* glw   = ws + 32960;    // 16384
    float* c1    = ws + 49344;    // 262144
    float* c2    = ws + 311488;   // 524288
    float* y1    = ws + 835776;   // 2048
    float* y2    = ws + 837824;   // 2048
    float* xfrac = ws + 839872;   // 16384
    float* z1    = ws + 856256;   // 2048
    float* z2    = ws + 858304;   // 2048

    k_glw<<<64, 256, 0, stream>>>(glw, ws);

    k_conv1<<<64, 256, 0, stream>>>(x, conv1_w, conv1_b, c1, stats);
    k_conv2<<<256, 256, 0, stream>>>(c1, stats, bn1_g, bn1_b, conv2_w, conv2_b,
                                     c2, stats + 32);
    k_conv3<<<256, 256, 0, stream>>>(c2, stats + 32, bn2_g, bn2_b, conv3_w, conv3_b,
                                     xflat);

    gemv_block<true><<<2048, 256, 0, stream>>>(enc_w1, enc_b1, xflat, y1);
    gemv2<true><<<256, 256, 0, stream>>>(enc_w2, enc_b2, y1, y2);
    gemv2<false><<<2048, 256, 0, stream>>>(enc_w3, enc_b3, y2, xfrac);

    k_glconv<<<2080, 256, 0, stream>>>(glw, xfrac, xproc);

    gemv_block<true><<<2048, 256, 0, stream>>>(op_w1, op_b1, xproc, z1);
    gemv2<true><<<256, 256, 0, stream>>>(op_w2, op_b2, z1, z2);
    gemv2<false><<<2048, 256, 0, stream>>>(op_w3, op_b3, z2, out);
}